// Round 1
// baseline (521.179 us; speedup 1.0000x reference)
//
#include <hip/hip_runtime.h>

#define NB 32
#define NS 512
#define NC 256   // D == F == 256
#define KW 3

__device__ __forceinline__ float wave_reduce_sum(float v) {
#pragma unroll
    for (int m = 32; m >= 1; m >>= 1) v += __shfl_xor(v, m, 64);
    return v;
}

// One block = one (batch, 16-row tile). 256 threads, thread f computes 16 output rows
// for its feature f, then LN(F)+ReLU (+ optional final linear reduction).
template <bool FINAL>
__global__ __launch_bounds__(256, 4) void conv_ln(
    const float* __restrict__ in,    // [B,S,256]
    const float* __restrict__ w,     // [256,256,3]
    const float* __restrict__ bias,  // [256]
    const float* __restrict__ gamma, // [256]
    const float* __restrict__ beta,  // [256]
    const float* __restrict__ linw,  // [256] (FINAL only)
    const float* __restrict__ linb,  // [1]   (FINAL only)
    float* __restrict__ out)         // [B,S,256] or [B,S]
{
    __shared__ __align__(16) float xs[18 * 256];  // input rows; reused as h-tile for LN

    const int tid = threadIdx.x;
    const int blk = blockIdx.x;
    const int b   = blk >> 5;         // 32 tiles of 16 rows per batch
    const int s0  = (blk & 31) << 4;

    // Stage rows s0-1 .. s0+16 (zero-padded at batch edges)
    const float* inb = in + ((size_t)b * NS) * NC;
#pragma unroll
    for (int r = 0; r < 18; ++r) {
        int s = s0 + r - 1;
        float v = 0.f;
        if (s >= 0 && s < NS) v = inb[(size_t)s * NC + tid];
        xs[r * 256 + tid] = v;
    }
    __syncthreads();

    const int f = tid;
    float acc[16];
    const float bv = bias[f];
#pragma unroll
    for (int m = 0; m < 16; ++m) acc[m] = bv;

    const float* wf = w + (size_t)f * (NC * KW);
    for (int d4 = 0; d4 < NC; d4 += 4) {
        const float4 wa = *(const float4*)(wf + d4 * 3);
        const float4 wb = *(const float4*)(wf + d4 * 3 + 4);
        const float4 wc = *(const float4*)(wf + d4 * 3 + 8);
        float4 xv[18];
#pragma unroll
        for (int r = 0; r < 18; ++r) xv[r] = *(const float4*)&xs[r * 256 + d4];
#pragma unroll
        for (int m = 0; m < 16; ++m) {
            float a = acc[m];
            a = fmaf(xv[m].x,     wa.x, a);
            a = fmaf(xv[m + 1].x, wa.y, a);
            a = fmaf(xv[m + 2].x, wa.z, a);
            a = fmaf(xv[m].y,     wa.w, a);
            a = fmaf(xv[m + 1].y, wb.x, a);
            a = fmaf(xv[m + 2].y, wb.y, a);
            a = fmaf(xv[m].z,     wb.z, a);
            a = fmaf(xv[m + 1].z, wb.w, a);
            a = fmaf(xv[m + 2].z, wc.x, a);
            a = fmaf(xv[m].w,     wc.y, a);
            a = fmaf(xv[m + 1].w, wc.z, a);
            a = fmaf(xv[m + 2].w, wc.w, a);
            acc[m] = a;
        }
    }
    __syncthreads();   // done reading xs; reuse as LN tile

    float* hbuf = xs;  // [16][260] padded
#pragma unroll
    for (int m = 0; m < 16; ++m) hbuf[m * 260 + f] = acc[m];
    __syncthreads();

    const int wv = tid >> 6, lane = tid & 63;
#pragma unroll
    for (int rr = 0; rr < 4; ++rr) {
        const int m = wv * 4 + rr;
        const float v0 = hbuf[m * 260 + lane];
        const float v1 = hbuf[m * 260 + lane + 64];
        const float v2 = hbuf[m * 260 + lane + 128];
        const float v3 = hbuf[m * 260 + lane + 192];
        const float sum = wave_reduce_sum(v0 + v1 + v2 + v3);
        const float sq  = wave_reduce_sum(v0 * v0 + v1 * v1 + v2 * v2 + v3 * v3);
        const float mu  = sum * (1.f / 256.f);
        const float var = sq * (1.f / 256.f) - mu * mu;
        const float rs  = rsqrtf(var + 1e-5f);
        const float y0 = fmaxf(0.f, (v0 - mu) * rs * gamma[lane]       + beta[lane]);
        const float y1 = fmaxf(0.f, (v1 - mu) * rs * gamma[lane + 64]  + beta[lane + 64]);
        const float y2 = fmaxf(0.f, (v2 - mu) * rs * gamma[lane + 128] + beta[lane + 128]);
        const float y3 = fmaxf(0.f, (v3 - mu) * rs * gamma[lane + 192] + beta[lane + 192]);
        if constexpr (!FINAL) {
            float* orow = out + ((size_t)(b * NS + s0 + m)) * NC;
            orow[lane]       = y0;
            orow[lane + 64]  = y1;
            orow[lane + 128] = y2;
            orow[lane + 192] = y3;
        } else {
            float p = y0 * linw[lane] + y1 * linw[lane + 64] +
                      y2 * linw[lane + 128] + y3 * linw[lane + 192];
            p = wave_reduce_sum(p);
            if (lane == 0) out[b * NS + s0 + m] = fmaxf(0.f, p + linb[0]);
        }
    }
}

// Per-batch inclusive cumsum of rintf(target) -> ends[B,512]
__global__ __launch_bounds__(256) void scan_kernel(const float* __restrict__ target,
                                                   float* __restrict__ ends)
{
    __shared__ float bufa[512], bufb[512];
    const int b = blockIdx.x, t = threadIdx.x;
    const float* tb = target + (size_t)b * NS;
    bufa[t]       = rintf(tb[t]);
    bufa[t + 256] = rintf(tb[t + 256]);
    __syncthreads();
    float* src = bufa;
    float* dst = bufb;
    for (int off = 1; off < 512; off <<= 1) {
        for (int i = t; i < 512; i += 256) {
            float v = src[i];
            if (i >= off) v += src[i - off];
            dst[i] = v;
        }
        __syncthreads();
        float* tmp = src; src = dst; dst = tmp;
    }
    ends[(size_t)b * NS + t]       = src[t];
    ends[(size_t)b * NS + t + 256] = src[t + 256];
}

// Each block: 8 output frames of one batch; binary-search the interval, copy x-row.
__global__ __launch_bounds__(256) void gather_kernel(const float* __restrict__ x,
                                                     const float* __restrict__ ends,
                                                     float* __restrict__ out, int L)
{
    const int b   = blockIdx.y;
    const int t0  = blockIdx.x * 8;
    const int tid = threadIdx.x;
    const float* eb = ends + (size_t)b * NS;
    const float total = eb[511];
    for (int i = 0; i < 8; ++i) {
        const int t = t0 + i;
        if (t >= L) return;
        const float tf = (float)t;
        float v = 0.f;
        if (tf < total) {
            int pos = 0;  // first index with ends[pos] > tf
#pragma unroll
            for (int st = 256; st > 0; st >>= 1)
                if (eb[pos + st - 1] <= tf) pos += st;
            v = x[((size_t)(b * NS + pos)) * NC + tid];
        }
        out[((size_t)b * L + t) * NC + tid] = v;
    }
}

extern "C" void kernel_launch(void* const* d_in, const int* in_sizes, int n_in,
                              void* d_out, int out_size, void* d_ws, size_t ws_size,
                              hipStream_t stream)
{
    const float* x    = (const float*)d_in[0];
    const float* targ = (const float*)d_in[1];
    const float* c1w  = (const float*)d_in[2];
    const float* c1b  = (const float*)d_in[3];
    const float* c2w  = (const float*)d_in[4];
    const float* c2b  = (const float*)d_in[5];
    const float* n1g  = (const float*)d_in[6];
    const float* n1b  = (const float*)d_in[7];
    const float* n2g  = (const float*)d_in[8];
    const float* n2b  = (const float*)d_in[9];
    const float* lw   = (const float*)d_in[10];
    const float* lb   = (const float*)d_in[11];

    const int L = (out_size - NB * NS) / (NB * NC);

    float* h1   = (float*)d_ws;                       // [B,S,256] f32
    float* ends = h1 + (size_t)NB * NS * NC;          // [B,512]
    float* out  = (float*)d_out;                      // [B,L,256]
    float* pred = out + (size_t)NB * (size_t)L * NC;  // [B,S]

    conv_ln<false><<<dim3(NB * 32), 256, 0, stream>>>(x, c1w, c1b, n1g, n1b,
                                                      nullptr, nullptr, h1);
    conv_ln<true><<<dim3(NB * 32), 256, 0, stream>>>(h1, c2w, c2b, n2g, n2b,
                                                     lw, lb, pred);
    scan_kernel<<<dim3(NB), 256, 0, stream>>>(targ, ends);
    gather_kernel<<<dim3((L + 7) / 8, NB), 256, 0, stream>>>(x, ends, out, L);
}

// Round 3
// 185.182 us; speedup vs baseline: 2.8144x; 2.8144x over previous
//
#include <hip/hip_runtime.h>
#include <hip/hip_bf16.h>

#define NB 32
#define NS 512
#define NC 256
#define NKSTEP 24      // K=768 im2col / 32
#define ROWS 32        // output rows per block
#define HALO_ROWS 34

typedef __attribute__((ext_vector_type(8))) short short8;
typedef __attribute__((ext_vector_type(4))) float f32x4;

__device__ __forceinline__ unsigned pack2(float a, float b) {
    __hip_bfloat16 ha = __float2bfloat16(a), hb = __float2bfloat16(b);
    return ((unsigned)(*(unsigned short*)&hb) << 16) | (unsigned)(*(unsigned short*)&ha);
}

// Repack w[f][d][k] (f32) -> Bp[kstep][f][kgroup][8] (bf16), k_total = shift*256+d
__global__ __launch_bounds__(256) void prep_w(const float* __restrict__ w,
                                              unsigned short* __restrict__ Bp) {
    const int f = blockIdx.x, t = threadIdx.x;
    const float* wf = w + (size_t)f * 768 + t * 3;
    const float v[3] = {wf[0], wf[1], wf[2]};
#pragma unroll
    for (int shift = 0; shift < 3; ++shift) {
        const int k = shift * 256 + t;
        const int o = f * 32 + (k >> 5) * 8192 + (k & 31);
        __hip_bfloat16 h = __float2bfloat16(v[shift]);
        Bp[o] = *(unsigned short*)&h;
    }
}

// Fused conv1d(K=3) + LayerNorm + ReLU (+ final linear) via bf16 MFMA.
// Block: 32 rows x 256 cols, 4 waves (wave w owns 64-col strip).
template <bool FINAL, typename Tin>
__global__ __launch_bounds__(256, 2) void conv_mfma(
    const Tin* __restrict__ in,          // [B,S,256] float or bf16(ushort)
    const uint4* __restrict__ Bp,        // prepped weights (16B units)
    const float* __restrict__ bias,
    const float* __restrict__ gamma,
    const float* __restrict__ beta,
    const float* __restrict__ linw,
    const float* __restrict__ linb,
    void* __restrict__ outp)             // ushort* h1 (bf16) or float* pred
{
    __shared__ __align__(16) uint4 xs[HALO_ROWS * 32];  // 34 rows x 256 bf16, swizzled
    __shared__ float red[ROWS][4][2];
    __shared__ float dotb[ROWS][4];

    const int tid = threadIdx.x;
    const int b   = blockIdx.x >> 4;
    const int s0  = (blockIdx.x & 15) << 5;

    // ---- stage rows s0-1 .. s0+32 as bf16, XOR-swizzled (slot ^= (row&7)<<2) ----
    {
        const int slot = tid & 31;
        for (int r = tid >> 5; r < HALO_ROWS; r += 8) {
            const int s = s0 - 1 + r;
            uint4 v = {0u, 0u, 0u, 0u};
            if (s >= 0 && s < NS) {
                if constexpr (sizeof(Tin) == 4) {
                    const float* src = (const float*)in + ((size_t)(b * NS + s)) * NC + slot * 8;
                    const float4 lo = *(const float4*)src;
                    const float4 hi = *(const float4*)(src + 4);
                    v.x = pack2(lo.x, lo.y); v.y = pack2(lo.z, lo.w);
                    v.z = pack2(hi.x, hi.y); v.w = pack2(hi.z, hi.w);
                } else {
                    v = *(const uint4*)((const unsigned short*)in +
                                        ((size_t)(b * NS + s)) * NC + slot * 8);
                }
            }
            xs[r * 32 + (slot ^ ((r & 7) << 2))] = v;
        }
    }
    __syncthreads();

    const int lane = tid & 63;
    const int w    = tid >> 6;
    const int n0   = w << 6;
    const int l15  = lane & 15;
    const int lg   = lane >> 4;

    f32x4 acc[2][4];
#pragma unroll
    for (int mi = 0; mi < 2; ++mi)
#pragma unroll
        for (int ni = 0; ni < 4; ++ni) acc[mi][ni] = (f32x4){0.f, 0.f, 0.f, 0.f};

    const uint4* bbase = Bp + (size_t)(n0 + l15) * 4 + lg;

    auto lda = [&](int ks, int mi) -> short8 {
        const int row  = mi * 16 + l15 + (ks >> 3);          // + shift
        int slot = ((ks & 7) << 2) + lg;
        slot ^= (row & 7) << 2;
        return *(const short8*)&xs[row * 32 + slot];
    };
    auto ldb = [&](int ks, int ni) -> short8 {
        return *(const short8*)(const void*)(bbase + ks * 1024 + ni * 64);
    };

    short8 a0[2], b0[4], a1[2], b1[4];
#pragma unroll
    for (int mi = 0; mi < 2; ++mi) a0[mi] = lda(0, mi);
#pragma unroll
    for (int ni = 0; ni < 4; ++ni) b0[ni] = ldb(0, ni);

    for (int ks = 0; ks < NKSTEP; ks += 2) {
#pragma unroll
        for (int ni = 0; ni < 4; ++ni) b1[ni] = ldb(ks + 1, ni);
#pragma unroll
        for (int mi = 0; mi < 2; ++mi) a1[mi] = lda(ks + 1, mi);
#pragma unroll
        for (int mi = 0; mi < 2; ++mi)
#pragma unroll
            for (int ni = 0; ni < 4; ++ni)
                acc[mi][ni] = __builtin_amdgcn_mfma_f32_16x16x32_bf16(
                    a0[mi], b0[ni], acc[mi][ni], 0, 0, 0);
        if (ks + 2 < NKSTEP) {
#pragma unroll
            for (int ni = 0; ni < 4; ++ni) b0[ni] = ldb(ks + 2, ni);
#pragma unroll
            for (int mi = 0; mi < 2; ++mi) a0[mi] = lda(ks + 2, mi);
        }
#pragma unroll
        for (int mi = 0; mi < 2; ++mi)
#pragma unroll
            for (int ni = 0; ni < 4; ++ni)
                acc[mi][ni] = __builtin_amdgcn_mfma_f32_16x16x32_bf16(
                    a1[mi], b1[ni], acc[mi][ni], 0, 0, 0);
    }

    // ---- epilogue: bias, LN stats (16-lane shfl + cross-wave LDS), norm+ReLU ----
    float bv[4], gv[4], bt[4], lwv[4];
#pragma unroll
    for (int ni = 0; ni < 4; ++ni) {
        const int col = n0 + ni * 16 + l15;
        bv[ni] = bias[col]; gv[ni] = gamma[col]; bt[ni] = beta[col];
        if constexpr (FINAL) lwv[ni] = linw[col];
    }
#pragma unroll
    for (int mi = 0; mi < 2; ++mi)
#pragma unroll
        for (int ni = 0; ni < 4; ++ni)
#pragma unroll
            for (int i = 0; i < 4; ++i) acc[mi][ni][i] += bv[ni];

#pragma unroll
    for (int mi = 0; mi < 2; ++mi) {
        float s[4] = {0, 0, 0, 0}, q[4] = {0, 0, 0, 0};
#pragma unroll
        for (int ni = 0; ni < 4; ++ni)
#pragma unroll
            for (int i = 0; i < 4; ++i) {
                const float v = acc[mi][ni][i];
                s[i] += v; q[i] += v * v;
            }
#pragma unroll
        for (int i = 0; i < 4; ++i)
#pragma unroll
            for (int m = 1; m < 16; m <<= 1) {
                s[i] += __shfl_xor(s[i], m, 64);
                q[i] += __shfl_xor(q[i], m, 64);
            }
        if (l15 == 0) {
#pragma unroll
            for (int i = 0; i < 4; ++i) {
                red[mi * 16 + lg * 4 + i][w][0] = s[i];
                red[mi * 16 + lg * 4 + i][w][1] = q[i];
            }
        }
    }
    __syncthreads();

#pragma unroll
    for (int mi = 0; mi < 2; ++mi) {
#pragma unroll
        for (int i = 0; i < 4; ++i) {
            const int row = mi * 16 + lg * 4 + i;
            float sum = 0.f, sq = 0.f;
#pragma unroll
            for (int ww = 0; ww < 4; ++ww) { sum += red[row][ww][0]; sq += red[row][ww][1]; }
            const float mu = sum * (1.f / 256.f);
            const float rs = rsqrtf(sq * (1.f / 256.f) - mu * mu + 1e-5f);
            float p = 0.f;
#pragma unroll
            for (int ni = 0; ni < 4; ++ni) {
                const float y = fmaxf(0.f, (acc[mi][ni][i] - mu) * rs * gv[ni] + bt[ni]);
                if constexpr (!FINAL) {
                    __hip_bfloat16 h = __float2bfloat16(y);
                    ((unsigned short*)outp)[((size_t)(b * NS + s0 + row)) * NC +
                                            n0 + ni * 16 + l15] = *(unsigned short*)&h;
                } else {
                    p += y * lwv[ni];
                }
            }
            if constexpr (FINAL) {
#pragma unroll
                for (int m = 1; m < 16; m <<= 1) p += __shfl_xor(p, m, 64);
                if (l15 == 0) dotb[row][w] = p;
            }
        }
    }
    if constexpr (FINAL) {
        __syncthreads();
        if (tid < ROWS) {
            const float tot = dotb[tid][0] + dotb[tid][1] + dotb[tid][2] + dotb[tid][3] + linb[0];
            ((float*)outp)[b * NS + s0 + tid] = fmaxf(0.f, tot);
        }
    }
}

// Per-batch inclusive cumsum of rintf(target) -> ends[B,512]
__global__ __launch_bounds__(256) void scan_kernel(const float* __restrict__ target,
                                                   float* __restrict__ ends)
{
    __shared__ float bufa[512], bufb[512];
    const int b = blockIdx.x, t = threadIdx.x;
    const float* tb = target + (size_t)b * NS;
    bufa[t]       = rintf(tb[t]);
    bufa[t + 256] = rintf(tb[t + 256]);
    __syncthreads();
    float* src = bufa;
    float* dst = bufb;
    for (int off = 1; off < 512; off <<= 1) {
        for (int i = t; i < 512; i += 256) {
            float v = src[i];
            if (i >= off) v += src[i - off];
            dst[i] = v;
        }
        __syncthreads();
        float* tmp = src; src = dst; dst = tmp;
    }
    ends[(size_t)b * NS + t]       = src[t];
    ends[(size_t)b * NS + t + 256] = src[t + 256];
}

__global__ __launch_bounds__(256) void gather_kernel(const float* __restrict__ x,
                                                     const float* __restrict__ ends,
                                                     float* __restrict__ out, int L)
{
    const int b   = blockIdx.y;
    const int t0  = blockIdx.x * 8;
    const int tid = threadIdx.x;
    const float* eb = ends + (size_t)b * NS;
    const float total = eb[511];
    for (int i = 0; i < 8; ++i) {
        const int t = t0 + i;
        if (t >= L) return;
        const float tf = (float)t;
        float v = 0.f;
        if (tf < total) {
            int pos = 0;
#pragma unroll
            for (int st = 256; st > 0; st >>= 1)
                if (eb[pos + st - 1] <= tf) pos += st;
            v = x[((size_t)(b * NS + pos)) * NC + tid];
        }
        out[((size_t)b * L + t) * NC + tid] = v;
    }
}

extern "C" void kernel_launch(void* const* d_in, const int* in_sizes, int n_in,
                              void* d_out, int out_size, void* d_ws, size_t ws_size,
                              hipStream_t stream)
{
    const float* x    = (const float*)d_in[0];
    const float* targ = (const float*)d_in[1];
    const float* c1w  = (const float*)d_in[2];
    const float* c1b  = (const float*)d_in[3];
    const float* c2w  = (const float*)d_in[4];
    const float* c2b  = (const float*)d_in[5];
    const float* n1g  = (const float*)d_in[6];
    const float* n1b  = (const float*)d_in[7];
    const float* n2g  = (const float*)d_in[8];
    const float* n2b  = (const float*)d_in[9];
    const float* lw   = (const float*)d_in[10];
    const float* lb   = (const float*)d_in[11];

    const int L = (out_size - NB * NS) / (NB * NC);

    unsigned short* Bp1 = (unsigned short*)d_ws;          // 196608 bf16
    unsigned short* Bp2 = Bp1 + 196608;                   // 196608 bf16
    unsigned short* h1  = Bp2 + 196608;                   // [B,S,256] bf16
    float* ends = (float*)(h1 + (size_t)NB * NS * NC);    // [B,512]
    float* out  = (float*)d_out;                          // [B,L,256]
    float* pred = out + (size_t)NB * (size_t)L * NC;      // [B,S]

    prep_w<<<dim3(256), 256, 0, stream>>>(c1w, Bp1);
    prep_w<<<dim3(256), 256, 0, stream>>>(c2w, Bp2);

    conv_mfma<false, float><<<dim3(NB * 16), 256, 0, stream>>>(
        x, (const uint4*)Bp1, c1b, n1g, n1b, nullptr, nullptr, (void*)h1);
    conv_mfma<true, unsigned short><<<dim3(NB * 16), 256, 0, stream>>>(
        h1, (const uint4*)Bp2, c2b, n2g, n2b, lw, lb, (void*)pred);

    scan_kernel<<<dim3(NB), 256, 0, stream>>>(targ, ends);
    gather_kernel<<<dim3((L + 7) / 8, NB), 256, 0, stream>>>(x, ends, out, L);
}

// Round 4
// 162.017 us; speedup vs baseline: 3.2168x; 1.1430x over previous
//
#include <hip/hip_runtime.h>
#include <hip/hip_bf16.h>

#define NB 32
#define NS 512
#define NC 256
#define NKSTEP 24      // K=768 im2col / 32
#define ROWS 32        // output rows per block
#define HALO_ROWS 34

typedef __attribute__((ext_vector_type(8))) short short8;
typedef __attribute__((ext_vector_type(4))) float f32x4;

__device__ __forceinline__ unsigned pack2(float a, float b) {
    __hip_bfloat16 ha = __float2bfloat16(a), hb = __float2bfloat16(b);
    return ((unsigned)(*(unsigned short*)&hb) << 16) | (unsigned)(*(unsigned short*)&ha);
}

// Repack both weight tensors w[f][d][k] (f32) -> Bp[kstep][f][kgroup][8] (bf16)
__global__ __launch_bounds__(256) void prep_w2(const float* __restrict__ w1,
                                               const float* __restrict__ w2,
                                               unsigned short* __restrict__ Bp1,
                                               unsigned short* __restrict__ Bp2) {
    const bool second = blockIdx.x >= 256;
    const int f = blockIdx.x & 255, t = threadIdx.x;
    const float* w = second ? w2 : w1;
    unsigned short* Bp = second ? Bp2 : Bp1;
    const float* wf = w + (size_t)f * 768 + t * 3;
    const float v[3] = {wf[0], wf[1], wf[2]};
#pragma unroll
    for (int shift = 0; shift < 3; ++shift) {
        const int k = shift * 256 + t;
        const int o = f * 32 + (k >> 5) * 8192 + (k & 31);
        __hip_bfloat16 h = __float2bfloat16(v[shift]);
        Bp[o] = *(unsigned short*)&h;
    }
}

// Fused conv1d(K=3) + LayerNorm + ReLU (+ final linear) via bf16 MFMA.
// Block: 32 rows x 256 cols, 4 waves (wave w owns a 64-col strip).
// K-loop fully unrolled; B held in a 4-kstep register ring (static indices).
template <bool FINAL, typename Tin>
__global__ __launch_bounds__(256, 2) void conv_mfma(
    const Tin* __restrict__ in,          // [B,S,256] float or bf16(ushort)
    const uint4* __restrict__ Bp,        // prepped weights (16B units)
    const float* __restrict__ bias,
    const float* __restrict__ gamma,
    const float* __restrict__ beta,
    const float* __restrict__ linw,
    const float* __restrict__ linb,
    void* __restrict__ outp)             // ushort* h1 (bf16) or float* pred
{
    __shared__ __align__(16) uint4 xs[HALO_ROWS * 32];  // 34 rows x 256 bf16, swizzled
    __shared__ float red[ROWS][4][2];
    __shared__ float dotb[ROWS][4];

    const int tid = threadIdx.x;
    const int b   = blockIdx.x >> 4;
    const int s0  = (blockIdx.x & 15) << 5;

    // ---- stage rows s0-1 .. s0+32 as bf16, XOR-swizzled (slot ^= (row&7)<<2) ----
    {
        const int slot = tid & 31;
        for (int r = tid >> 5; r < HALO_ROWS; r += 8) {
            const int s = s0 - 1 + r;
            uint4 v = {0u, 0u, 0u, 0u};
            if (s >= 0 && s < NS) {
                if constexpr (sizeof(Tin) == 4) {
                    const float* src = (const float*)in + ((size_t)(b * NS + s)) * NC + slot * 8;
                    const float4 lo = *(const float4*)src;
                    const float4 hi = *(const float4*)(src + 4);
                    v.x = pack2(lo.x, lo.y); v.y = pack2(lo.z, lo.w);
                    v.z = pack2(hi.x, hi.y); v.w = pack2(hi.z, hi.w);
                } else {
                    v = *(const uint4*)((const unsigned short*)in +
                                        ((size_t)(b * NS + s)) * NC + slot * 8);
                }
            }
            xs[r * 32 + (slot ^ ((r & 7) << 2))] = v;
        }
    }
    __syncthreads();

    const int lane = tid & 63;
    const int w    = tid >> 6;
    const int n0   = w << 6;
    const int l15  = lane & 15;
    const int lg   = lane >> 4;

    f32x4 acc[2][4];
#pragma unroll
    for (int mi = 0; mi < 2; ++mi)
#pragma unroll
        for (int ni = 0; ni < 4; ++ni) acc[mi][ni] = (f32x4){0.f, 0.f, 0.f, 0.f};

    const uint4* bbase = Bp + (size_t)(n0 + l15) * 4 + lg;

    auto lda = [&](int ks, int mi) -> short8 {
        const int row  = mi * 16 + l15 + (ks >> 3);          // + shift
        int slot = ((ks & 7) << 2) + lg;
        slot ^= (row & 7) << 2;
        return *(const short8*)&xs[row * 32 + slot];
    };
    auto ldb = [&](int ks, int ni) -> short8 {
        return *(const short8*)(const void*)(bbase + ks * 1024 + ni * 64);
    };

    short8 areg[2][2], breg[4][4];
#pragma unroll
    for (int q = 0; q < 4; ++q)
#pragma unroll
        for (int ni = 0; ni < 4; ++ni) breg[q][ni] = ldb(q, ni);
#pragma unroll
    for (int p = 0; p < 2; ++p)
#pragma unroll
        for (int mi = 0; mi < 2; ++mi) areg[p][mi] = lda(p, mi);

#pragma unroll
    for (int p = 0; p < NKSTEP; ++p) {
        const int bs = p & 3, as = p & 1;
#pragma unroll
        for (int mi = 0; mi < 2; ++mi)
#pragma unroll
            for (int ni = 0; ni < 4; ++ni)
                acc[mi][ni] = __builtin_amdgcn_mfma_f32_16x16x32_bf16(
                    areg[as][mi], breg[bs][ni], acc[mi][ni], 0, 0, 0);
        if (p + 4 < NKSTEP) {
#pragma unroll
            for (int ni = 0; ni < 4; ++ni) breg[bs][ni] = ldb(p + 4, ni);
        }
        if (p + 2 < NKSTEP) {
#pragma unroll
            for (int mi = 0; mi < 2; ++mi) areg[as][mi] = lda(p + 2, mi);
        }
    }

    // ---- epilogue: bias, LN stats (16-lane shfl + cross-wave LDS), norm+ReLU ----
    float bv[4], gv[4], bt[4], lwv[4];
#pragma unroll
    for (int ni = 0; ni < 4; ++ni) {
        const int col = n0 + ni * 16 + l15;
        bv[ni] = bias[col]; gv[ni] = gamma[col]; bt[ni] = beta[col];
        if constexpr (FINAL) lwv[ni] = linw[col];
    }
#pragma unroll
    for (int mi = 0; mi < 2; ++mi)
#pragma unroll
        for (int ni = 0; ni < 4; ++ni)
#pragma unroll
            for (int i = 0; i < 4; ++i) acc[mi][ni][i] += bv[ni];

#pragma unroll
    for (int mi = 0; mi < 2; ++mi) {
        float s[4] = {0, 0, 0, 0}, q[4] = {0, 0, 0, 0};
#pragma unroll
        for (int ni = 0; ni < 4; ++ni)
#pragma unroll
            for (int i = 0; i < 4; ++i) {
                const float v = acc[mi][ni][i];
                s[i] += v; q[i] += v * v;
            }
#pragma unroll
        for (int i = 0; i < 4; ++i)
#pragma unroll
            for (int m = 1; m < 16; m <<= 1) {
                s[i] += __shfl_xor(s[i], m, 64);
                q[i] += __shfl_xor(q[i], m, 64);
            }
        if (l15 == 0) {
#pragma unroll
            for (int i = 0; i < 4; ++i) {
                red[mi * 16 + lg * 4 + i][w][0] = s[i];
                red[mi * 16 + lg * 4 + i][w][1] = q[i];
            }
        }
    }
    __syncthreads();

#pragma unroll
    for (int mi = 0; mi < 2; ++mi) {
#pragma unroll
        for (int i = 0; i < 4; ++i) {
            const int row = mi * 16 + lg * 4 + i;
            float sum = 0.f, sq = 0.f;
#pragma unroll
            for (int ww = 0; ww < 4; ++ww) { sum += red[row][ww][0]; sq += red[row][ww][1]; }
            const float mu = sum * (1.f / 256.f);
            const float rs = rsqrtf(sq * (1.f / 256.f) - mu * mu + 1e-5f);
            float p = 0.f;
#pragma unroll
            for (int ni = 0; ni < 4; ++ni) {
                const float y = fmaxf(0.f, (acc[mi][ni][i] - mu) * rs * gv[ni] + bt[ni]);
                if constexpr (!FINAL) {
                    __hip_bfloat16 h = __float2bfloat16(y);
                    ((unsigned short*)outp)[((size_t)(b * NS + s0 + row)) * NC +
                                            n0 + ni * 16 + l15] = *(unsigned short*)&h;
                } else {
                    p += y * lwv[ni];
                }
            }
            if constexpr (FINAL) {
#pragma unroll
                for (int m = 1; m < 16; m <<= 1) p += __shfl_xor(p, m, 64);
                if (l15 == 0) dotb[row][w] = p;
            }
        }
    }
    if constexpr (FINAL) {
        __syncthreads();
        if (tid < ROWS) {
            const float tot = dotb[tid][0] + dotb[tid][1] + dotb[tid][2] + dotb[tid][3] + linb[0];
            ((float*)outp)[b * NS + s0 + tid] = fmaxf(0.f, tot);
        }
    }
}

// Per-batch: cumsum of rint(target) in LDS, then SCATTER frame->source-row map.
// idx[b*L + t] = s for t in [start_s, end_s); -1 for the tail (t >= total).
__global__ __launch_bounds__(256) void scan_scatter(const float* __restrict__ target,
                                                    int* __restrict__ idx, int L)
{
    __shared__ int bufa[512], bufb[512];
    const int b = blockIdx.x, t = threadIdx.x;
    const float* tb = target + (size_t)b * NS;
    const int d0 = (int)rintf(tb[t]);
    const int d1 = (int)rintf(tb[t + 256]);
    bufa[t] = d0; bufa[t + 256] = d1;
    __syncthreads();
    int* src = bufa;
    int* dst = bufb;
    for (int off = 1; off < 512; off <<= 1) {
        for (int i = t; i < 512; i += 256) {
            int v = src[i];
            if (i >= off) v += src[i - off];
            dst[i] = v;
        }
        __syncthreads();
        int* tmp = src; src = dst; dst = tmp;
    }
    const int e0 = src[t], e1 = src[t + 256], total = src[511];
    int* ib = idx + (size_t)b * L;
    for (int k = e0 - d0; k < e0; ++k) ib[k] = t;
    for (int k = e1 - d1; k < e1; ++k) ib[k] = t + 256;
    for (int k = total + t; k < L; k += 256) ib[k] = -1;
}

// One wave = one output frame: 64 lanes x float4 = 1KB row copy, no search.
__global__ __launch_bounds__(256) void gather2(const float4* __restrict__ x4,
                                               const int* __restrict__ idx,
                                               float4* __restrict__ out4, int L)
{
    const int b     = blockIdx.y;
    const int frame = blockIdx.x * 4 + (threadIdx.x >> 6);
    const int lane  = threadIdx.x & 63;
    if (frame >= L) return;
    const int pos = idx[(size_t)b * L + frame];
    float4 v = {0.f, 0.f, 0.f, 0.f};
    if (pos >= 0) v = x4[(((size_t)(b * NS + pos)) << 6) + lane];
    out4[(((size_t)b * L + frame) << 6) + lane] = v;
}

extern "C" void kernel_launch(void* const* d_in, const int* in_sizes, int n_in,
                              void* d_out, int out_size, void* d_ws, size_t ws_size,
                              hipStream_t stream)
{
    const float* x    = (const float*)d_in[0];
    const float* targ = (const float*)d_in[1];
    const float* c1w  = (const float*)d_in[2];
    const float* c1b  = (const float*)d_in[3];
    const float* c2w  = (const float*)d_in[4];
    const float* c2b  = (const float*)d_in[5];
    const float* n1g  = (const float*)d_in[6];
    const float* n1b  = (const float*)d_in[7];
    const float* n2g  = (const float*)d_in[8];
    const float* n2b  = (const float*)d_in[9];
    const float* lw   = (const float*)d_in[10];
    const float* lb   = (const float*)d_in[11];

    const int L = (out_size - NB * NS) / (NB * NC);

    unsigned short* Bp1 = (unsigned short*)d_ws;          // 196608 bf16
    unsigned short* Bp2 = Bp1 + 196608;                   // 196608 bf16
    unsigned short* h1  = Bp2 + 196608;                   // [B,S,256] bf16
    int* idx = (int*)(h1 + (size_t)NB * NS * NC);         // [B,L]
    float* out  = (float*)d_out;                          // [B,L,256]
    float* pred = out + (size_t)NB * (size_t)L * NC;      // [B,S]

    prep_w2<<<dim3(512), 256, 0, stream>>>(c1w, c2w, Bp1, Bp2);

    conv_mfma<false, float><<<dim3(NB * 16), 256, 0, stream>>>(
        x, (const uint4*)Bp1, c1b, n1g, n1b, nullptr, nullptr, (void*)h1);
    conv_mfma<true, unsigned short><<<dim3(NB * 16), 256, 0, stream>>>(
        h1, (const uint4*)Bp2, c2b, n2g, n2b, lw, lb, (void*)pred);

    scan_scatter<<<dim3(NB), 256, 0, stream>>>(targ, idx, L);
    gather2<<<dim3((L + 3) / 4, NB), 256, 0, stream>>>(
        (const float4*)x, idx, (float4*)out, L);
}

// Round 5
// 158.654 us; speedup vs baseline: 3.2850x; 1.0212x over previous
//
#include <hip/hip_runtime.h>
#include <hip/hip_bf16.h>

#define NB 32
#define NS 512
#define NC 256
#define NKSTEP 24      // K=768 im2col / 32
#define ROWS 32        // output rows per block
#define HALO_ROWS 34

typedef __attribute__((ext_vector_type(8))) short short8;
typedef __attribute__((ext_vector_type(4))) float f32x4;

__device__ __forceinline__ unsigned pack2(float a, float b) {
    __hip_bfloat16 ha = __float2bfloat16(a), hb = __float2bfloat16(b);
    return ((unsigned)(*(unsigned short*)&hb) << 16) | (unsigned)(*(unsigned short*)&ha);
}

// blocks 0..511: repack weights w[f][d][k] -> Bp[kstep][f][kgroup][8] bf16
// blocks 512..543: per-batch cumsum of rint(target) + scatter frame->row map
__global__ __launch_bounds__(256) void prep_and_scan(
    const float* __restrict__ w1, const float* __restrict__ w2,
    unsigned short* __restrict__ Bp1, unsigned short* __restrict__ Bp2,
    const float* __restrict__ target, int* __restrict__ idx, int L)
{
    __shared__ int bufa[512], bufb[512];
    const int t = threadIdx.x;

    if (blockIdx.x < 512) {
        const bool second = blockIdx.x >= 256;
        const int f = blockIdx.x & 255;
        const float* w = second ? w2 : w1;
        unsigned short* Bp = second ? Bp2 : Bp1;
        const float* wf = w + (size_t)f * 768 + t * 3;
        const float v[3] = {wf[0], wf[1], wf[2]};
#pragma unroll
        for (int shift = 0; shift < 3; ++shift) {
            const int k = shift * 256 + t;
            const int o = f * 32 + (k >> 5) * 8192 + (k & 31);
            __hip_bfloat16 h = __float2bfloat16(v[shift]);
            Bp[o] = *(unsigned short*)&h;
        }
        return;
    }

    const int b = blockIdx.x - 512;
    const float* tb = target + (size_t)b * NS;
    const int d0 = (int)rintf(tb[t]);
    const int d1 = (int)rintf(tb[t + 256]);
    bufa[t] = d0; bufa[t + 256] = d1;
    __syncthreads();
    int* src = bufa;
    int* dst = bufb;
    for (int off = 1; off < 512; off <<= 1) {
        for (int i = t; i < 512; i += 256) {
            int v = src[i];
            if (i >= off) v += src[i - off];
            dst[i] = v;
        }
        __syncthreads();
        int* tmp = src; src = dst; dst = tmp;
    }
    const int e0 = src[t], e1 = src[t + 256], total = src[511];
    int* ib = idx + (size_t)b * L;
    // clamp to L: ends[511] (sum of rounded) can exceed L (round of sum)
    const int hi0 = e0 < L ? e0 : L;
    const int hi1 = e1 < L ? e1 : L;
    for (int k = e0 - d0; k < hi0; ++k) ib[k] = t;
    for (int k = e1 - d1; k < hi1; ++k) ib[k] = t + 256;
    for (int k = total + t; k < L; k += 256) ib[k] = -1;
}

// Fused conv1d(K=3) + LayerNorm + ReLU (+ final linear) via bf16 MFMA.
// Block: 32 rows x 256 cols, 4 waves (wave w owns a 64-col strip).
// 4 blocks/CU (VGPR<=128): B ring depth 2, A ring depth 2, K fully unrolled.
template <bool FINAL, typename Tin>
__global__ __launch_bounds__(256, 4) void conv_mfma(
    const Tin* __restrict__ in,          // [B,S,256] float or bf16(ushort)
    const uint4* __restrict__ Bp,        // prepped weights (16B units)
    const float* __restrict__ bias,
    const float* __restrict__ gamma,
    const float* __restrict__ beta,
    const float* __restrict__ linw,
    const float* __restrict__ linb,
    void* __restrict__ outp)             // ushort* h1 (bf16) or float* pred
{
    __shared__ __align__(16) uint4 xs[HALO_ROWS * 32];  // 34 rows x 256 bf16, swizzled
    __shared__ float red[ROWS][4][2];
    __shared__ float dotb[ROWS][4];

    const int tid = threadIdx.x;
    const int b   = blockIdx.x >> 4;
    const int s0  = (blockIdx.x & 15) << 5;

    // ---- stage rows s0-1 .. s0+32 as bf16, XOR-swizzled (slot ^= (row&7)<<2) ----
    {
        const int slot = tid & 31;
        for (int r = tid >> 5; r < HALO_ROWS; r += 8) {
            const int s = s0 - 1 + r;
            uint4 v = {0u, 0u, 0u, 0u};
            if (s >= 0 && s < NS) {
                if constexpr (sizeof(Tin) == 4) {
                    const float* src = (const float*)in + ((size_t)(b * NS + s)) * NC + slot * 8;
                    const float4 lo = *(const float4*)src;
                    const float4 hi = *(const float4*)(src + 4);
                    v.x = pack2(lo.x, lo.y); v.y = pack2(lo.z, lo.w);
                    v.z = pack2(hi.x, hi.y); v.w = pack2(hi.z, hi.w);
                } else {
                    v = *(const uint4*)((const unsigned short*)in +
                                        ((size_t)(b * NS + s)) * NC + slot * 8);
                }
            }
            xs[r * 32 + (slot ^ ((r & 7) << 2))] = v;
        }
    }
    __syncthreads();

    const int lane = tid & 63;
    const int w    = tid >> 6;
    const int n0   = w << 6;
    const int l15  = lane & 15;
    const int lg   = lane >> 4;

    f32x4 acc[2][4];
#pragma unroll
    for (int mi = 0; mi < 2; ++mi)
#pragma unroll
        for (int ni = 0; ni < 4; ++ni) acc[mi][ni] = (f32x4){0.f, 0.f, 0.f, 0.f};

    const uint4* bbase = Bp + (size_t)(n0 + l15) * 4 + lg;

    auto lda = [&](int ks, int mi) -> short8 {
        const int row  = mi * 16 + l15 + (ks >> 3);          // + shift
        int slot = ((ks & 7) << 2) + lg;
        slot ^= (row & 7) << 2;
        return *(const short8*)&xs[row * 32 + slot];
    };
    auto ldb = [&](int ks, int ni) -> short8 {
        return *(const short8*)(const void*)(bbase + ks * 1024 + ni * 64);
    };

    short8 areg[2][2], breg[2][4];
#pragma unroll
    for (int q = 0; q < 2; ++q) {
#pragma unroll
        for (int ni = 0; ni < 4; ++ni) breg[q][ni] = ldb(q, ni);
#pragma unroll
        for (int mi = 0; mi < 2; ++mi) areg[q][mi] = lda(q, mi);
    }

#pragma unroll
    for (int p = 0; p < NKSTEP; ++p) {
        const int rs = p & 1;
#pragma unroll
        for (int mi = 0; mi < 2; ++mi)
#pragma unroll
            for (int ni = 0; ni < 4; ++ni)
                acc[mi][ni] = __builtin_amdgcn_mfma_f32_16x16x32_bf16(
                    areg[rs][mi], breg[rs][ni], acc[mi][ni], 0, 0, 0);
        if (p + 2 < NKSTEP) {
#pragma unroll
            for (int ni = 0; ni < 4; ++ni) breg[rs][ni] = ldb(p + 2, ni);
#pragma unroll
            for (int mi = 0; mi < 2; ++mi) areg[rs][mi] = lda(p + 2, mi);
        }
    }

    // ---- epilogue: bias, LN stats (16-lane shfl + cross-wave LDS), norm+ReLU ----
    float bv[4], gv[4], bt[4], lwv[4];
#pragma unroll
    for (int ni = 0; ni < 4; ++ni) {
        const int col = n0 + ni * 16 + l15;
        bv[ni] = bias[col]; gv[ni] = gamma[col]; bt[ni] = beta[col];
        if constexpr (FINAL) lwv[ni] = linw[col];
    }
#pragma unroll
    for (int mi = 0; mi < 2; ++mi)
#pragma unroll
        for (int ni = 0; ni < 4; ++ni)
#pragma unroll
            for (int i = 0; i < 4; ++i) acc[mi][ni][i] += bv[ni];

#pragma unroll
    for (int mi = 0; mi < 2; ++mi) {
        float s[4] = {0, 0, 0, 0}, q[4] = {0, 0, 0, 0};
#pragma unroll
        for (int ni = 0; ni < 4; ++ni)
#pragma unroll
            for (int i = 0; i < 4; ++i) {
                const float v = acc[mi][ni][i];
                s[i] += v; q[i] += v * v;
            }
#pragma unroll
        for (int i = 0; i < 4; ++i)
#pragma unroll
            for (int m = 1; m < 16; m <<= 1) {
                s[i] += __shfl_xor(s[i], m, 64);
                q[i] += __shfl_xor(q[i], m, 64);
            }
        if (l15 == 0) {
#pragma unroll
            for (int i = 0; i < 4; ++i) {
                red[mi * 16 + lg * 4 + i][w][0] = s[i];
                red[mi * 16 + lg * 4 + i][w][1] = q[i];
            }
        }
    }
    __syncthreads();

#pragma unroll
    for (int mi = 0; mi < 2; ++mi) {
#pragma unroll
        for (int i = 0; i < 4; ++i) {
            const int row = mi * 16 + lg * 4 + i;
            float sum = 0.f, sq = 0.f;
#pragma unroll
            for (int ww = 0; ww < 4; ++ww) { sum += red[row][ww][0]; sq += red[row][ww][1]; }
            const float mu = sum * (1.f / 256.f);
            const float rs = rsqrtf(sq * (1.f / 256.f) - mu * mu + 1e-5f);
            float p = 0.f;
#pragma unroll
            for (int ni = 0; ni < 4; ++ni) {
                const float y = fmaxf(0.f, (acc[mi][ni][i] - mu) * rs * gv[ni] + bt[ni]);
                if constexpr (!FINAL) {
                    __hip_bfloat16 h = __float2bfloat16(y);
                    ((unsigned short*)outp)[((size_t)(b * NS + s0 + row)) * NC +
                                            n0 + ni * 16 + l15] = *(unsigned short*)&h;
                } else {
                    p += y * lwv[ni];
                }
            }
            if constexpr (FINAL) {
#pragma unroll
                for (int m = 1; m < 16; m <<= 1) p += __shfl_xor(p, m, 64);
                if (l15 == 0) dotb[row][w] = p;
            }
        }
    }
    if constexpr (FINAL) {
        __syncthreads();
        if (tid < ROWS) {
            const float tot = dotb[tid][0] + dotb[tid][1] + dotb[tid][2] + dotb[tid][3] + linb[0];
            ((float*)outp)[b * NS + s0 + tid] = fmaxf(0.f, tot);
        }
    }
}

// One wave = 2 consecutive output frames: 64 lanes x float4 = 1KB row copy each.
__global__ __launch_bounds__(256) void gather2(const float4* __restrict__ x4,
                                               const int* __restrict__ idx,
                                               float4* __restrict__ out4, int L)
{
    const int b    = blockIdx.y;
    const int f0   = blockIdx.x * 8 + (threadIdx.x >> 6) * 2;
    const int lane = threadIdx.x & 63;
#pragma unroll
    for (int j = 0; j < 2; ++j) {
        const int frame = f0 + j;
        if (frame >= L) return;
        const int pos = idx[(size_t)b * L + frame];
        float4 v = {0.f, 0.f, 0.f, 0.f};
        if (pos >= 0) v = x4[(((size_t)(b * NS + pos)) << 6) + lane];
        out4[(((size_t)b * L + frame) << 6) + lane] = v;
    }
}

extern "C" void kernel_launch(void* const* d_in, const int* in_sizes, int n_in,
                              void* d_out, int out_size, void* d_ws, size_t ws_size,
                              hipStream_t stream)
{
    const float* x    = (const float*)d_in[0];
    const float* targ = (const float*)d_in[1];
    const float* c1w  = (const float*)d_in[2];
    const float* c1b  = (const float*)d_in[3];
    const float* c2w  = (const float*)d_in[4];
    const float* c2b  = (const float*)d_in[5];
    const float* n1g  = (const float*)d_in[6];
    const float* n1b  = (const float*)d_in[7];
    const float* n2g  = (const float*)d_in[8];
    const float* n2b  = (const float*)d_in[9];
    const float* lw   = (const float*)d_in[10];
    const float* lb   = (const float*)d_in[11];

    const int L = (out_size - NB * NS) / (NB * NC);

    unsigned short* Bp1 = (unsigned short*)d_ws;          // 196608 bf16
    unsigned short* Bp2 = Bp1 + 196608;                   // 196608 bf16
    unsigned short* h1  = Bp2 + 196608;                   // [B,S,256] bf16
    int* idx = (int*)(h1 + (size_t)NB * NS * NC);         // [B,L]
    float* out  = (float*)d_out;                          // [B,L,256]
    float* pred = out + (size_t)NB * (size_t)L * NC;      // [B,S]

    prep_and_scan<<<dim3(512 + NB), 256, 0, stream>>>(c1w, c2w, Bp1, Bp2, targ, idx, L);

    conv_mfma<false, float><<<dim3(NB * 16), 256, 0, stream>>>(
        x, (const uint4*)Bp1, c1b, n1g, n1b, nullptr, nullptr, (void*)h1);
    conv_mfma<true, unsigned short><<<dim3(NB * 16), 256, 0, stream>>>(
        h1, (const uint4*)Bp2, c2b, n2g, n2b, lw, lb, (void*)pred);

    gather2<<<dim3((L + 7) / 8, NB), 256, 0, stream>>>(
        (const float4*)x, idx, (float4*)out, L);
}

// Round 6
// 153.971 us; speedup vs baseline: 3.3849x; 1.0304x over previous
//
#include <hip/hip_runtime.h>
#include <hip/hip_bf16.h>

#define NB 32
#define NS 512
#define NC 256
#define NKSTEP 24      // K=768 im2col / 32
#define TROWS 30       // useful output rows per conv block
#define NT 18          // tiles per batch: 18*30 = 540 >= 512
#define HROWS 32       // h rows per block (s0-1 .. s0+30)
#define XROWS 34       // x rows staged  (s0-2 .. s0+31)
#define CONV_BLOCKS (NB * NT)   // 576

typedef __attribute__((ext_vector_type(8))) short short8;
typedef __attribute__((ext_vector_type(4))) float f32x4;

__device__ __forceinline__ unsigned pack2(float a, float b) {
    __hip_bfloat16 ha = __float2bfloat16(a), hb = __float2bfloat16(b);
    return ((unsigned)(*(unsigned short*)&hb) << 16) | (unsigned)(*(unsigned short*)&ha);
}

// blocks 0..511: repack weights w[f][d][k] -> Bp[kstep][f][kgroup][8] bf16
// blocks 512..543: per-batch cumsum of rint(target) + scatter frame->row map
__global__ __launch_bounds__(256) void prep_and_scan(
    const float* __restrict__ w1, const float* __restrict__ w2,
    unsigned short* __restrict__ Bp1, unsigned short* __restrict__ Bp2,
    const float* __restrict__ target, int* __restrict__ idx, int L)
{
    __shared__ int bufa[512], bufb[512];
    const int t = threadIdx.x;

    if (blockIdx.x < 512) {
        const bool second = blockIdx.x >= 256;
        const int f = blockIdx.x & 255;
        const float* w = second ? w2 : w1;
        unsigned short* Bp = second ? Bp2 : Bp1;
        const float* wf = w + (size_t)f * 768 + t * 3;
        const float v[3] = {wf[0], wf[1], wf[2]};
#pragma unroll
        for (int shift = 0; shift < 3; ++shift) {
            const int k = shift * 256 + t;
            const int o = f * 32 + (k >> 5) * 8192 + (k & 31);
            __hip_bfloat16 h = __float2bfloat16(v[shift]);
            Bp[o] = *(unsigned short*)&h;
        }
        return;
    }

    const int b = blockIdx.x - 512;
    const float* tb = target + (size_t)b * NS;
    const int d0 = (int)rintf(tb[t]);
    const int d1 = (int)rintf(tb[t + 256]);
    bufa[t] = d0; bufa[t + 256] = d1;
    __syncthreads();
    int* src = bufa;
    int* dst = bufb;
    for (int off = 1; off < 512; off <<= 1) {
        for (int i = t; i < 512; i += 256) {
            int v = src[i];
            if (i >= off) v += src[i - off];
            dst[i] = v;
        }
        __syncthreads();
        int* tmp = src; src = dst; dst = tmp;
    }
    const int e0 = src[t], e1 = src[t + 256], total = src[511];
    int* ib = idx + (size_t)b * L;
    const int hi0 = e0 < L ? e0 : L;
    const int hi1 = e1 < L ? e1 : L;
    for (int k = e0 - d0; k < hi0; ++k) ib[k] = t;
    for (int k = e1 - d1; k < hi1; ++k) ib[k] = t + 256;
    for (int k = total + t; k < L; k += 256) ib[k] = -1;
}

// blocks < CONV_BLOCKS: fully-fused duration predictor
//   conv1(K=3)+LN+ReLU -> LDS h-tile (32 rows incl. halo, zero-padded at seq edges)
//   conv2(K=3)+LN+ReLU -> dot(lin_w)+ReLU -> pred (30 rows/block)
// blocks >= CONV_BLOCKS: length-regulator gather (one wave = 2 frames, 1KB row copies)
__global__ __launch_bounds__(256, 4) void fused_conv_gather(
    const float* __restrict__ x,
    const uint4* __restrict__ Bp1, const uint4* __restrict__ Bp2,
    const float* __restrict__ bias1, const float* __restrict__ g1, const float* __restrict__ be1,
    const float* __restrict__ bias2, const float* __restrict__ g2, const float* __restrict__ be2,
    const float* __restrict__ linw, const float* __restrict__ linb,
    const int* __restrict__ idx, float* __restrict__ pred,
    const float4* __restrict__ x4, float4* __restrict__ out4, int L)
{
    __shared__ __align__(16) uint4 xs[XROWS * 32];            // 34 x 256 bf16, swizzled
    __shared__ __align__(16) unsigned short hs[HROWS * 256];  // 32 x 256 bf16, swizzled
    __shared__ float red[HROWS][4][2];
    __shared__ float dotb[HROWS][4];

    const int tid = threadIdx.x;

    if (blockIdx.x >= CONV_BLOCKS) {
        // ---------------- gather path ----------------
        const int g    = blockIdx.x - CONV_BLOCKS;
        const int b    = g & 31;
        const int f0   = (g >> 5) * 8 + (tid >> 6) * 2;
        const int lane = tid & 63;
#pragma unroll
        for (int j = 0; j < 2; ++j) {
            const int frame = f0 + j;
            if (frame >= L) break;
            const int pos = idx[(size_t)b * L + frame];
            float4 v = {0.f, 0.f, 0.f, 0.f};
            if (pos >= 0) v = x4[(((size_t)(b * NS + pos)) << 6) + lane];
            out4[(((size_t)b * L + frame) << 6) + lane] = v;
        }
        return;
    }

    // ---------------- fused conv path ----------------
    const int b  = blockIdx.x / NT;
    const int t  = blockIdx.x - b * NT;
    const int s0 = t * TROWS;

    // stage x rows s0-2 .. s0+31 as bf16, swizzled (slot ^= (row&7)<<2)
    {
        const int slot = tid & 31;
        for (int r = tid >> 5; r < XROWS; r += 8) {
            const int s = s0 - 2 + r;
            uint4 v = {0u, 0u, 0u, 0u};
            if (s >= 0 && s < NS) {
                const float* src = x + ((size_t)(b * NS + s)) * NC + slot * 8;
                const float4 lo = *(const float4*)src;
                const float4 hi = *(const float4*)(src + 4);
                v.x = pack2(lo.x, lo.y); v.y = pack2(lo.z, lo.w);
                v.z = pack2(hi.x, hi.y); v.w = pack2(hi.z, hi.w);
            }
            xs[r * 32 + (slot ^ ((r & 7) << 2))] = v;
        }
    }
    __syncthreads();

    const int lane = tid & 63;
    const int w    = tid >> 6;
    const int n0   = w << 6;
    const int l15  = lane & 15;
    const int lg   = lane >> 4;

    auto ldax = [&](int ks, int mi) -> short8 {   // A-frag from xs (h row = mi*16+l15)
        const int row = mi * 16 + l15 + (ks >> 3);
        int slot = ((ks & 7) << 2) + lg;
        slot ^= (row & 7) << 2;
        return *(const short8*)&xs[row * 32 + slot];
    };
    auto ldah = [&](int ks, int mi) -> short8 {   // A-frag from hs (out row = mi*16+l15)
        const int row = mi * 16 + l15 + (ks >> 3);
        int slot = ((ks & 7) << 2) + lg;
        slot ^= (row & 7) << 2;
        return *(const short8*)&hs[row * 256 + slot * 8];
    };

    const uint4* bb1 = Bp1 + (size_t)(n0 + l15) * 4 + lg;
    const uint4* bb2 = Bp2 + (size_t)(n0 + l15) * 4 + lg;

    f32x4 acc[2][4];
    short8 areg[2][2], breg[2][4];

    // ======== conv1: h rows 0..31 (seq s0-1 .. s0+30) ========
#pragma unroll
    for (int mi = 0; mi < 2; ++mi)
#pragma unroll
        for (int ni = 0; ni < 4; ++ni) acc[mi][ni] = (f32x4){0.f, 0.f, 0.f, 0.f};
#pragma unroll
    for (int q = 0; q < 2; ++q) {
#pragma unroll
        for (int ni = 0; ni < 4; ++ni) breg[q][ni] = *(const short8*)(const void*)(bb1 + q * 1024 + ni * 64);
#pragma unroll
        for (int mi = 0; mi < 2; ++mi) areg[q][mi] = ldax(q, mi);
    }
#pragma unroll
    for (int p = 0; p < NKSTEP; ++p) {
        const int rs = p & 1;
#pragma unroll
        for (int mi = 0; mi < 2; ++mi)
#pragma unroll
            for (int ni = 0; ni < 4; ++ni)
                acc[mi][ni] = __builtin_amdgcn_mfma_f32_16x16x32_bf16(
                    areg[rs][mi], breg[rs][ni], acc[mi][ni], 0, 0, 0);
        if (p + 2 < NKSTEP) {
#pragma unroll
            for (int ni = 0; ni < 4; ++ni) breg[rs][ni] = *(const short8*)(const void*)(bb1 + (p + 2) * 1024 + ni * 64);
#pragma unroll
            for (int mi = 0; mi < 2; ++mi) areg[rs][mi] = ldax(p + 2, mi);
        }
    }

    // LN1 stats
    {
        float bv[4];
#pragma unroll
        for (int ni = 0; ni < 4; ++ni) bv[ni] = bias1[n0 + ni * 16 + l15];
#pragma unroll
        for (int mi = 0; mi < 2; ++mi) {
            float s[4] = {0, 0, 0, 0}, q[4] = {0, 0, 0, 0};
#pragma unroll
            for (int ni = 0; ni < 4; ++ni)
#pragma unroll
                for (int i = 0; i < 4; ++i) {
                    const float v = (acc[mi][ni][i] += bv[ni]);
                    s[i] += v; q[i] += v * v;
                }
#pragma unroll
            for (int i = 0; i < 4; ++i)
#pragma unroll
                for (int m = 1; m < 16; m <<= 1) {
                    s[i] += __shfl_xor(s[i], m, 64);
                    q[i] += __shfl_xor(q[i], m, 64);
                }
            if (l15 == 0) {
#pragma unroll
                for (int i = 0; i < 4; ++i) {
                    red[mi * 16 + lg * 4 + i][w][0] = s[i];
                    red[mi * 16 + lg * 4 + i][w][1] = q[i];
                }
            }
        }
    }
    __syncthreads();

    // LN1 apply + ReLU + zero seq-pad rows -> hs (swizzled bf16)
    {
        float gv[4], bt[4];
#pragma unroll
        for (int ni = 0; ni < 4; ++ni) { gv[ni] = g1[n0 + ni * 16 + l15]; bt[ni] = be1[n0 + ni * 16 + l15]; }
#pragma unroll
        for (int mi = 0; mi < 2; ++mi)
#pragma unroll
            for (int i = 0; i < 4; ++i) {
                const int row = mi * 16 + lg * 4 + i;
                const int sh  = s0 - 1 + row;            // global seq index of this h row
                const bool ok = (sh >= 0) && (sh < NS);
                float sum = 0.f, sq = 0.f;
#pragma unroll
                for (int ww = 0; ww < 4; ++ww) { sum += red[row][ww][0]; sq += red[row][ww][1]; }
                const float mu = sum * (1.f / 256.f);
                const float rs = rsqrtf(sq * (1.f / 256.f) - mu * mu + 1e-5f);
#pragma unroll
                for (int ni = 0; ni < 4; ++ni) {
                    const int col = n0 + ni * 16 + l15;
                    float y = fmaxf(0.f, (acc[mi][ni][i] - mu) * rs * gv[ni] + bt[ni]);
                    if (!ok) y = 0.f;
                    __hip_bfloat16 hv = __float2bfloat16(y);
                    const int slot = (col >> 3) ^ ((row & 7) << 2);
                    hs[row * 256 + slot * 8 + (col & 7)] = *(unsigned short*)&hv;
                }
            }
    }
    __syncthreads();

    // ======== conv2: out rows 0..31 (seq s0 .. s0+31), rows >= TROWS discarded ========
#pragma unroll
    for (int mi = 0; mi < 2; ++mi)
#pragma unroll
        for (int ni = 0; ni < 4; ++ni) acc[mi][ni] = (f32x4){0.f, 0.f, 0.f, 0.f};
#pragma unroll
    for (int q = 0; q < 2; ++q) {
#pragma unroll
        for (int ni = 0; ni < 4; ++ni) breg[q][ni] = *(const short8*)(const void*)(bb2 + q * 1024 + ni * 64);
#pragma unroll
        for (int mi = 0; mi < 2; ++mi) areg[q][mi] = ldah(q, mi);
    }
#pragma unroll
    for (int p = 0; p < NKSTEP; ++p) {
        const int rs = p & 1;
#pragma unroll
        for (int mi = 0; mi < 2; ++mi)
#pragma unroll
            for (int ni = 0; ni < 4; ++ni)
                acc[mi][ni] = __builtin_amdgcn_mfma_f32_16x16x32_bf16(
                    areg[rs][mi], breg[rs][ni], acc[mi][ni], 0, 0, 0);
        if (p + 2 < NKSTEP) {
#pragma unroll
            for (int ni = 0; ni < 4; ++ni) breg[rs][ni] = *(const short8*)(const void*)(bb2 + (p + 2) * 1024 + ni * 64);
#pragma unroll
            for (int mi = 0; mi < 2; ++mi) areg[rs][mi] = ldah(p + 2, mi);
        }
    }

    // LN2 stats
    {
        float bv[4];
#pragma unroll
        for (int ni = 0; ni < 4; ++ni) bv[ni] = bias2[n0 + ni * 16 + l15];
#pragma unroll
        for (int mi = 0; mi < 2; ++mi) {
            float s[4] = {0, 0, 0, 0}, q[4] = {0, 0, 0, 0};
#pragma unroll
            for (int ni = 0; ni < 4; ++ni)
#pragma unroll
                for (int i = 0; i < 4; ++i) {
                    const float v = (acc[mi][ni][i] += bv[ni]);
                    s[i] += v; q[i] += v * v;
                }
#pragma unroll
            for (int i = 0; i < 4; ++i)
#pragma unroll
                for (int m = 1; m < 16; m <<= 1) {
                    s[i] += __shfl_xor(s[i], m, 64);
                    q[i] += __shfl_xor(q[i], m, 64);
                }
            if (l15 == 0) {
#pragma unroll
                for (int i = 0; i < 4; ++i) {
                    red[mi * 16 + lg * 4 + i][w][0] = s[i];
                    red[mi * 16 + lg * 4 + i][w][1] = q[i];
                }
            }
        }
    }
    __syncthreads();

    // LN2 apply + ReLU + dot(lin_w) partials
    {
        float gv[4], bt[4], lwv[4];
#pragma unroll
        for (int ni = 0; ni < 4; ++ni) {
            const int col = n0 + ni * 16 + l15;
            gv[ni] = g2[col]; bt[ni] = be2[col]; lwv[ni] = linw[col];
        }
#pragma unroll
        for (int mi = 0; mi < 2; ++mi)
#pragma unroll
            for (int i = 0; i < 4; ++i) {
                const int row = mi * 16 + lg * 4 + i;
                float sum = 0.f, sq = 0.f;
#pragma unroll
                for (int ww = 0; ww < 4; ++ww) { sum += red[row][ww][0]; sq += red[row][ww][1]; }
                const float mu = sum * (1.f / 256.f);
                const float rs = rsqrtf(sq * (1.f / 256.f) - mu * mu + 1e-5f);
                float p = 0.f;
#pragma unroll
                for (int ni = 0; ni < 4; ++ni)
                    p += fmaxf(0.f, (acc[mi][ni][i] - mu) * rs * gv[ni] + bt[ni]) * lwv[ni];
#pragma unroll
                for (int m = 1; m < 16; m <<= 1) p += __shfl_xor(p, m, 64);
                if (l15 == 0) dotb[row][w] = p;
            }
    }
    __syncthreads();

    if (tid < TROWS && s0 + tid < NS) {
        const float tot = dotb[tid][0] + dotb[tid][1] + dotb[tid][2] + dotb[tid][3] + linb[0];
        pred[b * NS + s0 + tid] = fmaxf(0.f, tot);
    }
}

extern "C" void kernel_launch(void* const* d_in, const int* in_sizes, int n_in,
                              void* d_out, int out_size, void* d_ws, size_t ws_size,
                              hipStream_t stream)
{
    const float* x    = (const float*)d_in[0];
    const float* targ = (const float*)d_in[1];
    const float* c1w  = (const float*)d_in[2];
    const float* c1b  = (const float*)d_in[3];
    const float* c2w  = (const float*)d_in[4];
    const float* c2b  = (const float*)d_in[5];
    const float* n1g  = (const float*)d_in[6];
    const float* n1b  = (const float*)d_in[7];
    const float* n2g  = (const float*)d_in[8];
    const float* n2b  = (const float*)d_in[9];
    const float* lw   = (const float*)d_in[10];
    const float* lb   = (const float*)d_in[11];

    const int L = (out_size - NB * NS) / (NB * NC);

    unsigned short* Bp1 = (unsigned short*)d_ws;          // 196608 bf16
    unsigned short* Bp2 = Bp1 + 196608;                   // 196608 bf16
    int* idx = (int*)(Bp2 + 196608);                      // [B,L]
    float* out  = (float*)d_out;                          // [B,L,256]
    float* pred = out + (size_t)NB * (size_t)L * NC;      // [B,S]

    prep_and_scan<<<dim3(512 + NB), 256, 0, stream>>>(c1w, c2w, Bp1, Bp2, targ, idx, L);

    const int nfb = (L + 7) / 8;
    fused_conv_gather<<<dim3(CONV_BLOCKS + NB * nfb), 256, 0, stream>>>(
        x, (const uint4*)Bp1, (const uint4*)Bp2,
        c1b, n1g, n1b, c2b, n2g, n2b, lw, lb,
        idx, pred, (const float4*)x, (float4*)out, L);
}